// Round 4
// baseline (133.202 us; speedup 1.0000x reference)
//
#include <hip/hip_runtime.h>
#include <math.h>

#define VOCAB 50000
#define D_WORD 300
#define D_TOPIC 128
#define DH 312            // D_NOUN_HIDDEN
#define NB 8192
#define LMAX 32
#define N_MONTH 12

// ---------------------------------------------------------------------------
// Wave64 sum-reduce on the VALU pipe via DPP (no LDS-pipe ds_swizzle):
//   row_shr:1/2/4/8 accumulate within each 16-lane row, row_bcast:15/31
//   fold rows; full sum lands in lane 63; v_readlane broadcasts as SGPR.
// ---------------------------------------------------------------------------
__device__ __forceinline__ float wave_sum_uniform(float x) {
    int v = __float_as_int(x);
    int t;
#define DPP_STEP(ctrl)                                                   \
    t = __builtin_amdgcn_update_dpp(0, v, (ctrl), 0xf, 0xf, true);       \
    v = __float_as_int(__int_as_float(v) + __int_as_float(t));
    DPP_STEP(0x111)   // row_shr:1
    DPP_STEP(0x112)   // row_shr:2
    DPP_STEP(0x114)   // row_shr:4
    DPP_STEP(0x118)   // row_shr:8
    DPP_STEP(0x142)   // row_bcast:15
    DPP_STEP(0x143)   // row_bcast:31
#undef DPP_STEP
    return __int_as_float(__builtin_amdgcn_readlane(v, 63));
}

__device__ __forceinline__ float fexp2(float x) {
    return __builtin_amdgcn_exp2f(x);     // raw v_exp_f32 (2^x)
}

// ---------------------------------------------------------------------------
// Kernel 1: w = (k_w^T @ (q_w @ topic_emb + q_b)) * log2(e)/sqrt(128).
// log2(e) folded in so the attn kernel can use raw v_exp_f32 (2^x); the
// softmax is invariant under the base change.  FOUR blocks: each block
// redundantly computes query (64 KB q_w read) and produces 78 of the 312
// outputs, so the cold 160 KB k_w pull runs on 4 CUs instead of 1
// (this kernel is pure latency -- single block serialized it).
// ---------------------------------------------------------------------------
__global__ __launch_bounds__(128) void compute_w_kernel(
    const float* __restrict__ topic_emb,
    const float* __restrict__ q_w, const float* __restrict__ q_b,
    const float* __restrict__ k_w,
    float* __restrict__ w_out)
{
    __shared__ float query_s[D_TOPIC];
    __shared__ float topic_s[D_TOPIC];
    int t = threadIdx.x;                  // 0..127
    topic_s[t] = topic_emb[t];
    __syncthreads();
    {
        const float4* qr = (const float4*)(q_w + t * D_TOPIC);  // row-contig
        float q0 = q_b[t], q1 = 0.f, q2 = 0.f, q3 = 0.f;
        #pragma unroll 8
        for (int k4 = 0; k4 < D_TOPIC / 4; ++k4) {
            float4 v = qr[k4];
            q0 = fmaf(v.x, topic_s[4 * k4 + 0], q0);
            q1 = fmaf(v.y, topic_s[4 * k4 + 1], q1);
            q2 = fmaf(v.z, topic_s[4 * k4 + 2], q2);
            q3 = fmaf(v.w, topic_s[4 * k4 + 3], q3);
        }
        query_s[t] = (q0 + q1) + (q2 + q3);
    }
    __syncthreads();
    if (t < 78) {
        int o = blockIdx.x * 78 + t;      // 4 * 78 = 312 outputs
        float a0 = 0.f, a1 = 0.f, a2 = 0.f, a3 = 0.f;
        #pragma unroll 8
        for (int d = 0; d < D_TOPIC; d += 4) {        // coalesced over o
            a0 = fmaf(k_w[(d + 0) * DH + o], query_s[d + 0], a0);
            a1 = fmaf(k_w[(d + 1) * DH + o], query_s[d + 1], a1);
            a2 = fmaf(k_w[(d + 2) * DH + o], query_s[d + 2], a2);
            a3 = fmaf(k_w[(d + 3) * DH + o], query_s[d + 3], a3);
        }
        // 1/sqrt(128) * log2(e)
        w_out[o] = ((a0 + a1) + (a2 + a3))
                 * (0.08838834764831845f * 1.4426950408889634f);
    }
}

// ---------------------------------------------------------------------------
// Kernel 2 (fused, single pass): one WAVE per sample, online softmax,
// two tokens per iteration, ONE combined flash rescale per pair,
// 1-pair-deep software pipeline (loads for pair l+2 issued at top of
// iteration l).  Row ids are broadcast via v_readlane -> SGPR, so row
// bases are scalar (saddr loads, shared VGPR offset) -- no ds_bpermute
// on the critical path and less VGPR address math.  Scores are in the
// exp2 domain (log2e pre-folded into w).  Month one-hot written directly.
// ---------------------------------------------------------------------------
__global__ __launch_bounds__(256, 4) void attn_fused_kernel(
    const int* __restrict__ noun_ids, const int* __restrict__ lengths,
    const int* __restrict__ months, const int* __restrict__ encode_p,
    const float* __restrict__ we, const float* __restrict__ w,
    float* __restrict__ out)
{
    int wave = threadIdx.x >> 6, lane = threadIdx.x & 63;
    int b = blockIdx.x * 4 + wave;
    float4* ob = (float4*)(out + (size_t)b * DH);   // 78 float4, 16B-aligned
    int len = lengths[b];

    if (len <= 0) {                       // reference leaves empty rows zero;
        float4 z = {0.f, 0.f, 0.f, 0.f};  // d_out is poisoned -> must write
        ob[lane] = z;
        if (lane < 14) ob[64 + lane] = z;
        return;                           // len uniform per wave: no divergence
    }
    if (len > LMAX) len = LMAX;

    // w fragment in registers (same cols as this lane's row fragment)
    const float4* w4 = (const float4*)w;
    float4 ww = w4[lane];
    float4 wb = (lane < 11) ? w4[64 + lane] : (float4){0.f, 0.f, 0.f, 0.f};

    int id = (lane < LMAX) ? noun_ids[b * LMAX + lane] : 0;

    float m = -1e30f, denom = 0.f;        // online-softmax state (log2 domain)
    float4 acc0 = {0.f, 0.f, 0.f, 0.f};
    float4 acc1 = {0.f, 0.f, 0.f, 0.f};
    const float4 z4 = {0.f, 0.f, 0.f, 0.f};

    // ---- prologue: issue pair-0 loads (scalar row bases) --------------
    bool cdual = (len > 1);
    {
        int rid0 = __builtin_amdgcn_readlane(id, 0);
        int rid1 = __builtin_amdgcn_readlane(id, cdual ? 1 : 0);
        const float4* r0 = (const float4*)(we + (size_t)rid0 * D_WORD);
        const float4* r1 = (const float4*)(we + (size_t)rid1 * D_WORD);
        float4 cA0 = r0[lane];
        float4 cB0 = r1[lane];
        float4 cA1 = (lane < 11) ? r0[64 + lane] : z4;
        float4 cB1 = (lane < 11) ? r1[64 + lane] : z4;

        for (int l = 0; l < len; l += 2) {
            // ---- prefetch pair l+2 (re-fetch current on last iter:
            // harmless cache hits; keeps control flow + loads uniform) --
            int nl = (l + 2 < len) ? l + 2 : l;
            bool ndual = (nl + 1 < len);
            int nrid0 = __builtin_amdgcn_readlane(id, nl);
            int nrid1 = __builtin_amdgcn_readlane(id, ndual ? nl + 1 : nl);
            const float4* nr0 = (const float4*)(we + (size_t)nrid0 * D_WORD);
            const float4* nr1 = (const float4*)(we + (size_t)nrid1 * D_WORD);
            float4 nA0 = nr0[lane];
            float4 nB0 = nr1[lane];
            float4 nA1 = (lane < 11) ? nr0[64 + lane] : z4;
            float4 nB1 = (lane < 11) ? nr1[64 + lane] : z4;

            // ---- score current pair (w pre-scaled: 1/sqrt(128)*log2e) -
            float p0 = fmaf(cA0.x, ww.x, fmaf(cA0.y, ww.y,
                       fmaf(cA0.z, ww.z, fmaf(cA0.w, ww.w,
                       fmaf(cA1.x, wb.x, fmaf(cA1.y, wb.y,
                       fmaf(cA1.z, wb.z, cA1.w * wb.w)))))));
            float p1 = fmaf(cB0.x, ww.x, fmaf(cB0.y, ww.y,
                       fmaf(cB0.z, ww.z, fmaf(cB0.w, ww.w,
                       fmaf(cB1.x, wb.x, fmaf(cB1.y, wb.y,
                       fmaf(cB1.z, wb.z, cB1.w * wb.w)))))));
            p0 = wave_sum_uniform(p0);
            p1 = wave_sum_uniform(p1);
            if (!cdual) p1 = -1e30f;      // odd tail: e1 -> 0

            // ---- ONE combined flash rescale for the pair (exp2) ----
            float mn = fmaxf(fmaxf(m, p0), p1);   // v_max3_f32
            float c  = fexp2(m  - mn);            // 0 on first iter
            float e0 = fexp2(p0 - mn);
            float e1 = fexp2(p1 - mn);
            m = mn;
            denom = fmaf(denom, c, e0 + e1);
            acc0.x = fmaf(acc0.x, c, fmaf(e0, cA0.x, e1 * cB0.x));
            acc0.y = fmaf(acc0.y, c, fmaf(e0, cA0.y, e1 * cB0.y));
            acc0.z = fmaf(acc0.z, c, fmaf(e0, cA0.z, e1 * cB0.z));
            acc0.w = fmaf(acc0.w, c, fmaf(e0, cA0.w, e1 * cB0.w));
            acc1.x = fmaf(acc1.x, c, fmaf(e0, cA1.x, e1 * cB1.x));
            acc1.y = fmaf(acc1.y, c, fmaf(e0, cA1.y, e1 * cB1.y));
            acc1.z = fmaf(acc1.z, c, fmaf(e0, cA1.z, e1 * cB1.z));
            acc1.w = fmaf(acc1.w, c, fmaf(e0, cA1.w, e1 * cB1.w));

            // ---- rotate pipeline ----
            cA0 = nA0; cB0 = nB0; cA1 = nA1; cB1 = nB1; cdual = ndual;
        }
    }

    float rs = 1.f / denom;
    acc0.x *= rs; acc0.y *= rs; acc0.z *= rs; acc0.w *= rs;
    ob[lane] = acc0;
    if (lane < 11) {
        acc1.x *= rs; acc1.y *= rs; acc1.z *= rs; acc1.w *= rs;
        ob[64 + lane] = acc1;
    } else if (lane < 14) {
        int mo = months[b];
        float enc = (float)(*encode_p);
        int base = (lane - 11) * 4;
        float4 oh;
        oh.x = (base + 0 == mo) ? enc : 0.f;
        oh.y = (base + 1 == mo) ? enc : 0.f;
        oh.z = (base + 2 == mo) ? enc : 0.f;
        oh.w = (base + 3 == mo) ? enc : 0.f;
        ob[64 + lane] = oh;
    }
}

// ---------------------------------------------------------------------------
extern "C" void kernel_launch(void* const* d_in, const int* in_sizes, int n_in,
                              void* d_out, int out_size, void* d_ws, size_t ws_size,
                              hipStream_t stream) {
    const float* topic_emb = (const float*)d_in[0];
    const int*   noun_ids  = (const int*)d_in[1];
    const int*   lengths   = (const int*)d_in[2];
    const int*   months    = (const int*)d_in[3];
    const int*   encode    = (const int*)d_in[4];
    const float* we        = (const float*)d_in[5];
    const float* k_w       = (const float*)d_in[6];
    // d_in[7] = k_b: cancels in softmax, never touches `value` -> unused.
    const float* q_w       = (const float*)d_in[8];
    const float* q_b       = (const float*)d_in[9];
    float* out = (float*)d_out;

    float* w_vec = (float*)d_ws;         // 312 floats

    compute_w_kernel<<<4, 128, 0, stream>>>(topic_emb, q_w, q_b, k_w, w_vec);
    attn_fused_kernel<<<NB / 4, 256, 0, stream>>>(noun_ids, lengths, months,
                                                  encode, we, w_vec, out);
}